// Round 2
// baseline (1741.549 us; speedup 1.0000x reference)
//
#include <hip/hip_runtime.h>
#include <hip/hip_bf16.h>
#include <stdint.h>

// N=4096, NFEAT=1024, NHID=256, NHEADS=4, NCLASS=1024, NLAYERS=2
#define NN 4096
#define FF 1024
#define LOG2E 1.44269504088896340736f

typedef unsigned short u16;
typedef float f32x4 __attribute__((ext_vector_type(4)));
typedef __bf16 bf16x8 __attribute__((ext_vector_type(8)));

typedef __attribute__((address_space(1))) void gvoid_t;
typedef __attribute__((address_space(3))) void lvoid_t;

__device__ __forceinline__ u16 f2b(float f) {
  __bf16 b = (__bf16)f;
  return __builtin_bit_cast(u16, b);
}
__device__ __forceinline__ float b2f(u16 u) {
  return (float)__builtin_bit_cast(__bf16, u);
}
__device__ __forceinline__ void gload_lds16(const void* g, void* l) {
  __builtin_amdgcn_global_load_lds((gvoid_t*)g, (lvoid_t*)l, 16, 0, 0);
}

// ---------------- adjacency -> bitmask [4096][128] u32 ----------------
__global__ void k_pack(const int* __restrict__ adj, uint32_t* __restrict__ bits) {
  int gw = (blockIdx.x * 256 + threadIdx.x) >> 6;
  int lane = threadIdx.x & 63;
  int row = gw >> 6;
  int j0 = (gw & 63) << 6;
  int a = adj[(long)row * NN + j0 + lane];
  unsigned long long m = __ballot(a != 0);
  if (lane == 0)
    *reinterpret_cast<unsigned long long*>(&bits[row * 128 + (j0 >> 5)]) = m;
}

// ---------------- f32 -> bf16 convert (vectorized) ----------------
__global__ void k_cvt(const float* __restrict__ in, u16* __restrict__ out, int n4) {
  int i = blockIdx.x * 256 + threadIdx.x;
  if (i >= n4) return;
  float4 v = reinterpret_cast<const float4*>(in)[i];
  ushort4 o;
  o.x = f2b(v.x); o.y = f2b(v.y); o.z = f2b(v.z); o.w = f2b(v.w);
  reinterpret_cast<ushort4*>(out)[i] = o;
}

// ------------- batched transpose+convert: out[b][c][r] = bf16(in[b][r][c]) -------------
__global__ void k_tconv(const float* __restrict__ in, u16* __restrict__ out, int R, int C) {
  __shared__ float t[32][33];
  long bs = (long)R * C;
  const float* ip = in + blockIdx.z * bs;
  u16* op = out + blockIdx.z * bs;
  int r0 = blockIdx.x * 32, c0 = blockIdx.y * 32;
  int tx = threadIdx.x, ty = threadIdx.y;  // (32,8)
#pragma unroll
  for (int k = 0; k < 4; k++)
    t[ty + k * 8][tx] = ip[(long)(r0 + ty + k * 8) * C + c0 + tx];
  __syncthreads();
#pragma unroll
  for (int k = 0; k < 4; k++)
    op[(long)(c0 + ty + k * 8) * R + r0 + tx] = f2b(t[tx][ty + k * 8]);
}

// ------------- f_src/f_dst (scaled by log2e): s[h][i] = log2e * sum_c WhT[h*dh+c][i]*a[h][c] -------------
__global__ void k_fsd(const u16* __restrict__ WhT, const float* __restrict__ a,
                      float* __restrict__ s, float* __restrict__ d, int dh) {
  int i = blockIdx.x * 256 + threadIdx.x;
  int h = blockIdx.y;
  const u16* w = WhT + (long)h * dh * NN + i;
  const float* av = a + (long)h * 2 * dh;
  float ss = 0.f, dd = 0.f;
  for (int c = 0; c < dh; c++) {
    float v = b2f(w[(long)c * NN]);
    ss = fmaf(v, av[c], ss);
    dd = fmaf(v, av[dh + c], dd);
  }
  s[h * NN + i] = ss * LOG2E;
  d[h * NN + i] = dd * LOG2E;
}

// ------------- m[h][i] = lrelu(s[h][i] + max_{j in adj(i)} d[h][j]) -------------
template <int H>
__global__ void k_maxd(const uint32_t* __restrict__ bits, const float* __restrict__ s,
                       const float* __restrict__ d, float* __restrict__ m) {
  int wv = threadIdx.x >> 6, lane = threadIdx.x & 63;
  int row = blockIdx.x * 4 + wv;
  const uint32_t* br = bits + (long)row * 128;
  float mx[H];
#pragma unroll
  for (int h = 0; h < H; h++) mx[h] = -1e30f;
  for (int t = 0; t < 64; t++) {
    int j = t * 64 + lane;
    uint32_t wb = br[j >> 5];
    bool on = (wb >> (j & 31)) & 1u;
#pragma unroll
    for (int h = 0; h < H; h++) {
      float dv = d[h * NN + j];
      mx[h] = (on && dv > mx[h]) ? dv : mx[h];
    }
  }
#pragma unroll
  for (int h = 0; h < H; h++) {
    float v = mx[h];
#pragma unroll
    for (int o = 32; o >= 1; o >>= 1) v = fmaxf(v, __shfl_xor(v, o));
    if (lane == 0) {
      float e = s[h * NN + row] + v;
      m[h * NN + row] = fmaxf(e, 0.2f * e);
    }
  }
}

// ------------- bf16 GEMM C = A @ B given BT, writes CT[n][i] = bf16(C[i][n]) -------------
// A [M=4096][K] bf16 row-major, BT [N][K] bf16 row-major. 128x128 tile, BK=64, 4 waves 2x2.
__global__ __launch_bounds__(256, 2) void k_gemm(const u16* __restrict__ A,
                                                 const u16* __restrict__ BT,
                                                 u16* __restrict__ CT, int K) {
  __shared__ __align__(16) u16 As[128 * 64];
  __shared__ __align__(16) u16 Bs[128 * 64];
  int tid = threadIdx.x;
  int w = tid >> 6, lane = tid & 63;
  int i0 = blockIdx.x * 128, n0 = blockIdx.y * 128;
  int wr = w >> 1, wc = w & 1;
  int l15 = lane & 15, l4 = lane >> 4;

  f32x4 acc[4][4] = {};

  int srow = lane >> 3;
  int sj = ((lane & 7) ^ srow) * 8;  // pre-swizzled source chunk (chunk ^= row&7)

  for (int kt = 0; kt < K / 64; kt++) {
    int k0 = kt * 64;
    __syncthreads();
#pragma unroll
    for (int t = 0; t < 4; t++) {
      int r = w * 32 + t * 8 + srow;
      gload_lds16(A + (long)(i0 + r) * K + k0 + sj, &As[(w * 32 + t * 8) * 64]);
      gload_lds16(BT + (long)(n0 + r) * K + k0 + sj, &Bs[(w * 32 + t * 8) * 64]);
    }
    __syncthreads();
#pragma unroll
    for (int kc = 0; kc < 2; kc++) {
      bf16x8 af[4], bf[4];
#pragma unroll
      for (int mi = 0; mi < 4; mi++) {
        int r = wr * 64 + mi * 16 + l15;
        int ph = (kc * 4 + l4) ^ (r & 7);
        af[mi] = *reinterpret_cast<const bf16x8*>(&As[r * 64 + ph * 8]);
      }
#pragma unroll
      for (int ni = 0; ni < 4; ni++) {
        int r = wc * 64 + ni * 16 + l15;
        int ph = (kc * 4 + l4) ^ (r & 7);
        bf[ni] = *reinterpret_cast<const bf16x8*>(&Bs[r * 64 + ph * 8]);
      }
#pragma unroll
      for (int mi = 0; mi < 4; mi++)
#pragma unroll
        for (int ni = 0; ni < 4; ni++)
          acc[mi][ni] =
              __builtin_amdgcn_mfma_f32_16x16x32_bf16(af[mi], bf[ni], acc[mi][ni], 0, 0, 0);
    }
  }
#pragma unroll
  for (int mi = 0; mi < 4; mi++) {
    int i = i0 + wr * 64 + mi * 16 + l4 * 4;
#pragma unroll
    for (int ni = 0; ni < 4; ni++) {
      int n = n0 + wc * 64 + ni * 16 + l15;
      ushort4 o;
      o.x = f2b(acc[mi][ni][0]);
      o.y = f2b(acc[mi][ni][1]);
      o.z = f2b(acc[mi][ni][2]);
      o.w = f2b(acc[mi][ni][3]);
      *reinterpret_cast<ushort4*>(&CT[(long)n * NN + i]) = o;
    }
  }
}

// ------------- fused masked-softmax-attention @ Wh  (P generated in A-fragment layout) -------------
// MODE 0: heads  — cb = head, writes hout[i][cb*256+c] = bf16(elu(att@Wh))
// MODE 1: out    — cb = col-block, writes xout = xin + elu(att@Wh2), plus bf16 copy
// block: 4 waves, each 32 rows (M_rep=2) x 256 cols; K-loop over j (BK=64), Z row-sum in registers.
template <int MODE>
__global__ __launch_bounds__(256, 2) void k_pv(const uint32_t* __restrict__ bits,
                                               const u16* __restrict__ WT,
                                               const float* __restrict__ sA,
                                               const float* __restrict__ dA,
                                               const float* __restrict__ mA,
                                               u16* __restrict__ hout,
                                               const float* __restrict__ xin,
                                               float* __restrict__ xout,
                                               u16* __restrict__ xbout) {
  __shared__ __align__(16) u16 Bs[256 * 64];
  int tid = threadIdx.x;
  int w = tid >> 6, lane = tid & 63;
  int i0 = blockIdx.x * 128;
  int cb = blockIdx.y;
  int h = (MODE == 0) ? cb : 0;

  const u16* Bsrc = WT + (long)cb * 256 * NN;
  const float* dv = dA + (long)h * NN;
  int l15 = lane & 15, l4 = lane >> 4;
  int rbase = i0 + w * 32 + l15;
  float s0 = sA[h * NN + rbase], s1 = sA[h * NN + rbase + 16];
  float m0 = mA[h * NN + rbase], m1 = mA[h * NN + rbase + 16];
  const uint8_t* bb = reinterpret_cast<const uint8_t*>(bits);
  const uint8_t* br0 = bb + (long)rbase * 512;
  const uint8_t* br1 = br0 + 16 * 512;

  f32x4 acc[2][16] = {};
  float zp0 = 0.f, zp1 = 0.f;

  int srow = lane >> 3;
  int sj = ((lane & 7) ^ srow) * 8;

  for (int kt = 0; kt < 64; kt++) {
    int j0 = kt * 64;
    __syncthreads();
#pragma unroll
    for (int t = 0; t < 8; t++) {
      int c = w * 64 + t * 8 + srow;
      gload_lds16(Bsrc + (long)c * NN + j0 + sj, &Bs[(w * 64 + t * 8) * 64]);
    }
    __syncthreads();
#pragma unroll
    for (int kc = 0; kc < 2; kc++) {
      int jb = j0 + kc * 32 + l4 * 8;
      f32x4 dlo = *reinterpret_cast<const f32x4*>(&dv[jb]);
      f32x4 dhi = *reinterpret_cast<const f32x4*>(&dv[jb + 4]);
      uint32_t b0 = br0[jb >> 3], b1 = br1[jb >> 3];
      bf16x8 a0, a1;
#pragma unroll
      for (int e = 0; e < 8; e++) {
        float dj = (e < 4) ? dlo[e] : dhi[e - 4];
        float v0 = s0 + dj;
        v0 = fmaxf(v0, 0.2f * v0) - m0;          // lrelu - m   (log2 domain)
        float p0 = ((b0 >> e) & 1u) ? exp2f(v0) : 0.f;
        zp0 += p0;
        a0[e] = (__bf16)p0;
        float v1 = s1 + dj;
        v1 = fmaxf(v1, 0.2f * v1) - m1;
        float p1 = ((b1 >> e) & 1u) ? exp2f(v1) : 0.f;
        zp1 += p1;
        a1[e] = (__bf16)p1;
      }
#pragma unroll
      for (int nt = 0; nt < 16; nt++) {
        int c = nt * 16 + l15;
        int ph = (kc * 4 + l4) ^ (c & 7);
        bf16x8 bfr = *reinterpret_cast<const bf16x8*>(&Bs[c * 64 + ph * 8]);
        acc[0][nt] = __builtin_amdgcn_mfma_f32_16x16x32_bf16(a0, bfr, acc[0][nt], 0, 0, 0);
        acc[1][nt] = __builtin_amdgcn_mfma_f32_16x16x32_bf16(a1, bfr, acc[1][nt], 0, 0, 0);
      }
    }
  }
  float z0 = zp0, z1 = zp1;
  z0 += __shfl_xor(z0, 16);
  z0 += __shfl_xor(z0, 32);
  z1 += __shfl_xor(z1, 16);
  z1 += __shfl_xor(z1, 32);

#pragma unroll
  for (int mi = 0; mi < 2; mi++) {
    float zsrc = (mi == 0) ? z0 : z1;
    float zr[4];
#pragma unroll
    for (int r = 0; r < 4; r++) zr[r] = __shfl(zsrc, l4 * 4 + r);
#pragma unroll
    for (int nt = 0; nt < 16; nt++) {
      int col = cb * 256 + nt * 16 + l15;
#pragma unroll
      for (int r = 0; r < 4; r++) {
        int i = i0 + w * 32 + mi * 16 + l4 * 4 + r;
        float val = acc[mi][nt][r] / zr[r];
        float o = val > 0.f ? val : exp2f(val * LOG2E) - 1.f;  // elu
        long idx = (long)i * FF + col;
        if (MODE == 0) {
          hout[idx] = f2b(o);
        } else {
          float xn = xin[idx] + o;
          xout[idx] = xn;
          xbout[idx] = f2b(xn);
        }
      }
    }
  }
}

extern "C" void kernel_launch(void* const* d_in, const int* in_sizes, int n_in,
                              void* d_out, int out_size, void* d_ws, size_t ws_size,
                              hipStream_t stream) {
  const float* x = (const float*)d_in[0];
  const int* adj = (const int*)d_in[1];
  const float* W_heads = (const float*)d_in[2];  // [2][4][1024][256]
  const float* a_heads = (const float*)d_in[3];  // [2][4][512]
  const float* W_out = (const float*)d_in[4];    // [2][1024][1024]
  const float* a_out = (const float*)d_in[5];    // [2][2048]
  float* out = (float*)d_out;

  char* ws = (char*)d_ws;
  uint32_t* bits = (uint32_t*)(ws + 0x0);       // 2 MB
  u16* xb = (u16*)(ws + 0x200000);              // 8 MB  bf16 x / x_new
  u16* WcatT = (u16*)(ws + 0xA00000);           // 4 MB  [2][1024 n][1024 k]
  u16* WoutT = (u16*)(ws + 0xE00000);           // 4 MB
  u16* WhT = (u16*)(ws + 0x1200000);            // 8 MB  [1024][4096] (reused for Wh2)
  u16* hbuf = (u16*)(ws + 0x1A00000);           // 8 MB  h bf16 [4096][1024]
  float* xmid = (float*)(ws + 0x2200000);       // 16 MB x after layer 0
  float* s_h = (float*)(ws + 0x3200000);        // [4][4096]
  float* d_h = (float*)(ws + 0x3210000);
  float* m_h = (float*)(ws + 0x3220000);
  float* s_o = (float*)(ws + 0x3230000);        // [4096]
  float* d_o = (float*)(ws + 0x3234000);
  float* m_o = (float*)(ws + 0x3238000);

  k_pack<<<65536, 256, 0, stream>>>(adj, bits);
  k_cvt<<<4096, 256, 0, stream>>>(x, xb, NN * FF / 4);
  k_tconv<<<dim3(32, 8, 8), dim3(32, 8), 0, stream>>>(W_heads, WcatT, 1024, 256);
  k_tconv<<<dim3(32, 32, 2), dim3(32, 8), 0, stream>>>(W_out, WoutT, 1024, 1024);

  for (int l = 0; l < 2; l++) {
    k_gemm<<<dim3(32, 8), 256, 0, stream>>>(xb, WcatT + l * 1048576, WhT, FF);
    k_fsd<<<dim3(16, 4), 256, 0, stream>>>(WhT, a_heads + l * 2048, s_h, d_h, 256);
    k_maxd<4><<<1024, 256, 0, stream>>>(bits, s_h, d_h, m_h);
    k_pv<0><<<dim3(32, 4), 256, 0, stream>>>(bits, WhT, s_h, d_h, m_h, hbuf, nullptr,
                                             nullptr, nullptr);
    k_gemm<<<dim3(32, 8), 256, 0, stream>>>(hbuf, WoutT + l * 1048576, WhT, FF);
    k_fsd<<<dim3(16, 1), 256, 0, stream>>>(WhT, a_out + l * 2048, s_o, d_o, 1024);
    k_maxd<1><<<1024, 256, 0, stream>>>(bits, s_o, d_o, m_o);
    k_pv<1><<<dim3(32, 4), 256, 0, stream>>>(bits, WhT, s_o, d_o, m_o, nullptr,
                                             l ? xmid : x, l ? out : xmid, xb);
  }
}

// Round 3
// 1157.401 us; speedup vs baseline: 1.5047x; 1.5047x over previous
//
#include <hip/hip_runtime.h>
#include <hip/hip_bf16.h>
#include <stdint.h>

// N=4096, NFEAT=1024, NHID=256, NHEADS=4, NCLASS=1024, NLAYERS=2
#define NN 4096
#define FF 1024
#define LOG2E 1.44269504088896340736f

typedef unsigned short u16;
typedef float f32x4 __attribute__((ext_vector_type(4)));
typedef __bf16 bf16x8 __attribute__((ext_vector_type(8)));

typedef __attribute__((address_space(1))) void gvoid_t;
typedef __attribute__((address_space(3))) void lvoid_t;

__device__ __forceinline__ u16 f2b(float f) {
  __bf16 b = (__bf16)f;
  return __builtin_bit_cast(u16, b);
}
__device__ __forceinline__ float b2f(u16 u) {
  return (float)__builtin_bit_cast(__bf16, u);
}
__device__ __forceinline__ void gload_lds16(const void* g, void* l) {
  __builtin_amdgcn_global_load_lds((gvoid_t*)g, (lvoid_t*)l, 16, 0, 0);
}

// ---------------- adjacency -> bitmask [4096][128] u32 ----------------
__global__ void k_pack(const int* __restrict__ adj, uint32_t* __restrict__ bits) {
  int gw = (blockIdx.x * 256 + threadIdx.x) >> 6;
  int lane = threadIdx.x & 63;
  int row = gw >> 6;
  int j0 = (gw & 63) << 6;
  int a = adj[(long)row * NN + j0 + lane];
  unsigned long long m = __ballot(a != 0);
  if (lane == 0)
    *reinterpret_cast<unsigned long long*>(&bits[row * 128 + (j0 >> 5)]) = m;
}

// ---------------- f32 -> bf16 convert (vectorized) ----------------
__global__ void k_cvt(const float* __restrict__ in, u16* __restrict__ out, int n4) {
  int i = blockIdx.x * 256 + threadIdx.x;
  if (i >= n4) return;
  float4 v = reinterpret_cast<const float4*>(in)[i];
  ushort4 o;
  o.x = f2b(v.x); o.y = f2b(v.y); o.z = f2b(v.z); o.w = f2b(v.w);
  reinterpret_cast<ushort4*>(out)[i] = o;
}

// ------------- batched transpose+convert: out[b][c][r] = bf16(in[b][r][c]) -------------
__global__ void k_tconv(const float* __restrict__ in, u16* __restrict__ out, int R, int C) {
  __shared__ float t[32][33];
  long bs = (long)R * C;
  const float* ip = in + blockIdx.z * bs;
  u16* op = out + blockIdx.z * bs;
  int r0 = blockIdx.x * 32, c0 = blockIdx.y * 32;
  int tx = threadIdx.x, ty = threadIdx.y;  // (32,8)
#pragma unroll
  for (int k = 0; k < 4; k++)
    t[ty + k * 8][tx] = ip[(long)(r0 + ty + k * 8) * C + c0 + tx];
  __syncthreads();
#pragma unroll
  for (int k = 0; k < 4; k++)
    op[(long)(c0 + ty + k * 8) * R + r0 + tx] = f2b(t[tx][ty + k * 8]);
}

// ------------- f_src/f_dst (scaled by log2e), c-split with atomic reduce -------------
// s[h][i] += log2e * sum_{c in [c0,c0+32)} WhT[h*dh+c][i]*a_src[h][c]   (same for d with a_dst)
// grid: (NN/256, dh/32, H), block 256. s/d must be pre-zeroed.
__global__ void k_fsd2(const u16* __restrict__ WhT, const float* __restrict__ a,
                       float* __restrict__ s, float* __restrict__ d, int dh) {
  int i = blockIdx.x * 256 + threadIdx.x;
  int h = blockIdx.z;
  int c0 = blockIdx.y * 32;
  const u16* w = WhT + ((long)h * dh + c0) * NN + i;
  const float* as = a + (long)h * 2 * dh + c0;
  const float* ad = as + dh;
  float ss = 0.f, dd = 0.f;
#pragma unroll
  for (int c = 0; c < 32; c++) {
    float v = b2f(w[(long)c * NN]);
    ss = fmaf(v, as[c], ss);
    dd = fmaf(v, ad[c], dd);
  }
  atomicAdd(&s[h * NN + i], ss * LOG2E);
  atomicAdd(&d[h * NN + i], dd * LOG2E);
}

// ------------- m[h][i] = lrelu(s[h][i] + max_{j in adj(i)} d[h][j]) -------------
template <int H>
__global__ void k_maxd(const uint32_t* __restrict__ bits, const float* __restrict__ s,
                       const float* __restrict__ d, float* __restrict__ m) {
  int wv = threadIdx.x >> 6, lane = threadIdx.x & 63;
  int row = blockIdx.x * 4 + wv;
  const uint32_t* br = bits + (long)row * 128;
  float mx[H];
#pragma unroll
  for (int h = 0; h < H; h++) mx[h] = -1e30f;
  for (int t = 0; t < 64; t++) {
    int j = t * 64 + lane;
    uint32_t wb = br[j >> 5];
    bool on = (wb >> (j & 31)) & 1u;
#pragma unroll
    for (int h = 0; h < H; h++) {
      float dv = d[h * NN + j];
      mx[h] = (on && dv > mx[h]) ? dv : mx[h];
    }
  }
#pragma unroll
  for (int h = 0; h < H; h++) {
    float v = mx[h];
#pragma unroll
    for (int o = 32; o >= 1; o >>= 1) v = fmaxf(v, __shfl_xor(v, o));
    if (lane == 0) {
      float e = s[h * NN + row] + v;
      m[h * NN + row] = fmaxf(e, 0.2f * e);
    }
  }
}

// ------------- bf16 GEMM C = A @ B given BT, writes CT[n][i] = bf16(C[i][n]) -------------
// A [M=4096][K] bf16 row-major, BT [N][K] bf16 row-major. 128x128 tile, BK=64, 4 waves 2x2.
__global__ __launch_bounds__(256, 2) void k_gemm(const u16* __restrict__ A,
                                                 const u16* __restrict__ BT,
                                                 u16* __restrict__ CT, int K) {
  __shared__ __align__(16) u16 As[128 * 64];
  __shared__ __align__(16) u16 Bs[128 * 64];
  int tid = threadIdx.x;
  int w = tid >> 6, lane = tid & 63;
  int i0 = blockIdx.x * 128, n0 = blockIdx.y * 128;
  int wr = w >> 1, wc = w & 1;
  int l15 = lane & 15, l4 = lane >> 4;

  f32x4 acc[4][4] = {};

  int srow = lane >> 3;
  int sj = ((lane & 7) ^ srow) * 8;  // pre-swizzled source chunk (chunk ^= row&7)

  for (int kt = 0; kt < K / 64; kt++) {
    int k0 = kt * 64;
    __syncthreads();
#pragma unroll
    for (int t = 0; t < 4; t++) {
      int r = w * 32 + t * 8 + srow;
      gload_lds16(A + (long)(i0 + r) * K + k0 + sj, &As[(w * 32 + t * 8) * 64]);
      gload_lds16(BT + (long)(n0 + r) * K + k0 + sj, &Bs[(w * 32 + t * 8) * 64]);
    }
    __syncthreads();
#pragma unroll
    for (int kc = 0; kc < 2; kc++) {
      bf16x8 af[4], bf[4];
#pragma unroll
      for (int mi = 0; mi < 4; mi++) {
        int r = wr * 64 + mi * 16 + l15;
        int ph = (kc * 4 + l4) ^ (r & 7);
        af[mi] = *reinterpret_cast<const bf16x8*>(&As[r * 64 + ph * 8]);
      }
#pragma unroll
      for (int ni = 0; ni < 4; ni++) {
        int r = wc * 64 + ni * 16 + l15;
        int ph = (kc * 4 + l4) ^ (r & 7);
        bf[ni] = *reinterpret_cast<const bf16x8*>(&Bs[r * 64 + ph * 8]);
      }
#pragma unroll
      for (int mi = 0; mi < 4; mi++)
#pragma unroll
        for (int ni = 0; ni < 4; ni++)
          acc[mi][ni] =
              __builtin_amdgcn_mfma_f32_16x16x32_bf16(af[mi], bf[ni], acc[mi][ni], 0, 0, 0);
    }
  }
#pragma unroll
  for (int mi = 0; mi < 4; mi++) {
    int i = i0 + wr * 64 + mi * 16 + l4 * 4;
#pragma unroll
    for (int ni = 0; ni < 4; ni++) {
      int n = n0 + wc * 64 + ni * 16 + l15;
      ushort4 o;
      o.x = f2b(acc[mi][ni][0]);
      o.y = f2b(acc[mi][ni][1]);
      o.z = f2b(acc[mi][ni][2]);
      o.w = f2b(acc[mi][ni][3]);
      *reinterpret_cast<ushort4*>(&CT[(long)n * NN + i]) = o;
    }
  }
}

// ------------- fused masked-softmax-attention @ Wh  (P generated in A-fragment layout) -------------
// MODE 0: heads  — cb = head, writes hout[i][cb*256+c] = bf16(elu(att@Wh))
// MODE 1: out    — cb = col-block, writes xout = xin + elu(att@Wh2), plus bf16 copy
// block: 4 waves, each 32 rows (M_rep=2) x 256 cols; K-loop over j (BK=64), Z row-sum in registers.
template <int MODE>
__global__ __launch_bounds__(256, 2) void k_pv(const uint32_t* __restrict__ bits,
                                               const u16* __restrict__ WT,
                                               const float* __restrict__ sA,
                                               const float* __restrict__ dA,
                                               const float* __restrict__ mA,
                                               u16* __restrict__ hout,
                                               const float* __restrict__ xin,
                                               float* __restrict__ xout,
                                               u16* __restrict__ xbout) {
  __shared__ __align__(16) u16 Bs[256 * 64];
  int tid = threadIdx.x;
  int w = tid >> 6, lane = tid & 63;
  int i0 = blockIdx.x * 128;
  int cb = blockIdx.y;
  int h = (MODE == 0) ? cb : 0;

  const u16* Bsrc = WT + (long)cb * 256 * NN;
  const float* dv = dA + (long)h * NN;
  int l15 = lane & 15, l4 = lane >> 4;
  int rbase = i0 + w * 32 + l15;
  float s0 = sA[h * NN + rbase], s1 = sA[h * NN + rbase + 16];
  float m0 = mA[h * NN + rbase], m1 = mA[h * NN + rbase + 16];
  const uint8_t* bb = reinterpret_cast<const uint8_t*>(bits);
  const uint8_t* br0 = bb + (long)rbase * 512;
  const uint8_t* br1 = br0 + 16 * 512;

  f32x4 acc[2][16] = {};
  float zp0 = 0.f, zp1 = 0.f;

  int srow = lane >> 3;
  int sj = ((lane & 7) ^ srow) * 8;

  for (int kt = 0; kt < 64; kt++) {
    int j0 = kt * 64;
    __syncthreads();
#pragma unroll
    for (int t = 0; t < 8; t++) {
      int c = w * 64 + t * 8 + srow;
      gload_lds16(Bsrc + (long)c * NN + j0 + sj, &Bs[(w * 64 + t * 8) * 64]);
    }
    __syncthreads();
#pragma unroll
    for (int kc = 0; kc < 2; kc++) {
      int jb = j0 + kc * 32 + l4 * 8;
      f32x4 dlo = *reinterpret_cast<const f32x4*>(&dv[jb]);
      f32x4 dhi = *reinterpret_cast<const f32x4*>(&dv[jb + 4]);
      uint32_t b0 = br0[jb >> 3], b1 = br1[jb >> 3];
      bf16x8 a0, a1;
#pragma unroll
      for (int e = 0; e < 8; e++) {
        float dj = (e < 4) ? dlo[e] : dhi[e - 4];
        float v0 = s0 + dj;
        v0 = fmaxf(v0, 0.2f * v0) - m0;          // lrelu - m   (log2 domain)
        float p0 = ((b0 >> e) & 1u) ? exp2f(v0) : 0.f;
        zp0 += p0;
        a0[e] = (__bf16)p0;
        float v1 = s1 + dj;
        v1 = fmaxf(v1, 0.2f * v1) - m1;
        float p1 = ((b1 >> e) & 1u) ? exp2f(v1) : 0.f;
        zp1 += p1;
        a1[e] = (__bf16)p1;
      }
#pragma unroll
      for (int nt = 0; nt < 16; nt++) {
        int c = nt * 16 + l15;
        int ph = (kc * 4 + l4) ^ (c & 7);
        bf16x8 bfr = *reinterpret_cast<const bf16x8*>(&Bs[c * 64 + ph * 8]);
        acc[0][nt] = __builtin_amdgcn_mfma_f32_16x16x32_bf16(a0, bfr, acc[0][nt], 0, 0, 0);
        acc[1][nt] = __builtin_amdgcn_mfma_f32_16x16x32_bf16(a1, bfr, acc[1][nt], 0, 0, 0);
      }
    }
  }
  float z0 = zp0, z1 = zp1;
  z0 += __shfl_xor(z0, 16);
  z0 += __shfl_xor(z0, 32);
  z1 += __shfl_xor(z1, 16);
  z1 += __shfl_xor(z1, 32);

#pragma unroll
  for (int mi = 0; mi < 2; mi++) {
    float zsrc = (mi == 0) ? z0 : z1;
    float zr[4];
#pragma unroll
    for (int r = 0; r < 4; r++) zr[r] = __shfl(zsrc, l4 * 4 + r);
#pragma unroll
    for (int nt = 0; nt < 16; nt++) {
      int col = cb * 256 + nt * 16 + l15;
#pragma unroll
      for (int r = 0; r < 4; r++) {
        int i = i0 + w * 32 + mi * 16 + l4 * 4 + r;
        float val = acc[mi][nt][r] / zr[r];
        float o = val > 0.f ? val : exp2f(val * LOG2E) - 1.f;  // elu
        long idx = (long)i * FF + col;
        if (MODE == 0) {
          hout[idx] = f2b(o);
        } else {
          float xn = xin[idx] + o;
          xout[idx] = xn;
          xbout[idx] = f2b(xn);
        }
      }
    }
  }
}

extern "C" void kernel_launch(void* const* d_in, const int* in_sizes, int n_in,
                              void* d_out, int out_size, void* d_ws, size_t ws_size,
                              hipStream_t stream) {
  const float* x = (const float*)d_in[0];
  const int* adj = (const int*)d_in[1];
  const float* W_heads = (const float*)d_in[2];  // [2][4][1024][256]
  const float* a_heads = (const float*)d_in[3];  // [2][4][512]
  const float* W_out = (const float*)d_in[4];    // [2][1024][1024]
  const float* a_out = (const float*)d_in[5];    // [2][2048]
  float* out = (float*)d_out;

  char* ws = (char*)d_ws;
  uint32_t* bits = (uint32_t*)(ws + 0x0);       // 2 MB
  u16* xb = (u16*)(ws + 0x200000);              // 8 MB  bf16 x / x_new
  u16* WcatT = (u16*)(ws + 0xA00000);           // 4 MB  [2][1024 n][1024 k]
  u16* WoutT = (u16*)(ws + 0xE00000);           // 4 MB
  u16* WhT = (u16*)(ws + 0x1200000);            // 8 MB  [1024][4096] (reused for Wh2)
  u16* hbuf = (u16*)(ws + 0x1A00000);           // 8 MB  h bf16 [4096][1024]
  float* xmid = (float*)(ws + 0x2200000);       // 16 MB x after layer 0
  float* s_h = (float*)(ws + 0x3200000);        // [4][4096]
  float* d_h = (float*)(ws + 0x3210000);
  float* m_h = (float*)(ws + 0x3220000);
  float* s_o = (float*)(ws + 0x3230000);        // [4096]
  float* d_o = (float*)(ws + 0x3234000);
  float* m_o = (float*)(ws + 0x3238000);

  k_pack<<<65536, 256, 0, stream>>>(adj, bits);
  k_cvt<<<4096, 256, 0, stream>>>(x, xb, NN * FF / 4);
  k_tconv<<<dim3(32, 8, 8), dim3(32, 8), 0, stream>>>(W_heads, WcatT, 1024, 256);
  k_tconv<<<dim3(32, 32, 2), dim3(32, 8), 0, stream>>>(W_out, WoutT, 1024, 1024);

  for (int l = 0; l < 2; l++) {
    // zero the s/d/m stats region (s_h,d_h,m_h,s_o,d_o,m_o) for this layer
    hipMemsetAsync(ws + 0x3200000, 0, 0x3C000, stream);
    k_gemm<<<dim3(32, 8), 256, 0, stream>>>(xb, WcatT + l * 1048576, WhT, FF);
    k_fsd2<<<dim3(16, 8, 4), 256, 0, stream>>>(WhT, a_heads + l * 2048, s_h, d_h, 256);
    k_maxd<4><<<1024, 256, 0, stream>>>(bits, s_h, d_h, m_h);
    k_pv<0><<<dim3(32, 4), 256, 0, stream>>>(bits, WhT, s_h, d_h, m_h, hbuf, nullptr,
                                             nullptr, nullptr);
    k_gemm<<<dim3(32, 8), 256, 0, stream>>>(hbuf, WoutT + l * 1048576, WhT, FF);
    k_fsd2<<<dim3(16, 32, 1), 256, 0, stream>>>(WhT, a_out + l * 2048, s_o, d_o, 1024);
    k_maxd<1><<<1024, 256, 0, stream>>>(bits, s_o, d_o, m_o);
    k_pv<1><<<dim3(32, 4), 256, 0, stream>>>(bits, WhT, s_o, d_o, m_o, nullptr,
                                             l ? xmid : x, l ? out : xmid, xb);
  }
}

// Round 4
// 931.782 us; speedup vs baseline: 1.8691x; 1.2421x over previous
//
#include <hip/hip_runtime.h>
#include <hip/hip_bf16.h>
#include <stdint.h>

// N=4096, NFEAT=1024, NHID=256, NHEADS=4, NCLASS=1024, NLAYERS=2
#define NN 4096
#define FF 1024
#define LOG2E 1.44269504088896340736f

typedef unsigned short u16;
typedef float f32x4 __attribute__((ext_vector_type(4)));
typedef __bf16 bf16x8 __attribute__((ext_vector_type(8)));

typedef __attribute__((address_space(1))) void gvoid_t;
typedef __attribute__((address_space(3))) void lvoid_t;

__device__ __forceinline__ u16 f2b(float f) {
  __bf16 b = (__bf16)f;
  return __builtin_bit_cast(u16, b);
}
__device__ __forceinline__ float b2f(u16 u) {
  return (float)__builtin_bit_cast(__bf16, u);
}
__device__ __forceinline__ void gload_lds16(const void* g, void* l) {
  __builtin_amdgcn_global_load_lds((gvoid_t*)g, (lvoid_t*)l, 16, 0, 0);
}

// ---------------- adjacency -> bitmask [4096][128] u32 ----------------
__global__ void k_pack(const int* __restrict__ adj, uint32_t* __restrict__ bits) {
  int gw = (blockIdx.x * 256 + threadIdx.x) >> 6;
  int lane = threadIdx.x & 63;
  int row = gw >> 6;
  int j0 = (gw & 63) << 6;
  int a = adj[(long)row * NN + j0 + lane];
  unsigned long long m = __ballot(a != 0);
  if (lane == 0)
    *reinterpret_cast<unsigned long long*>(&bits[row * 128 + (j0 >> 5)]) = m;
}

// ---------------- f32 -> bf16 convert (vectorized) ----------------
__global__ void k_cvt(const float* __restrict__ in, u16* __restrict__ out, int n4) {
  int i = blockIdx.x * 256 + threadIdx.x;
  if (i >= n4) return;
  float4 v = reinterpret_cast<const float4*>(in)[i];
  ushort4 o;
  o.x = f2b(v.x); o.y = f2b(v.y); o.z = f2b(v.z); o.w = f2b(v.w);
  reinterpret_cast<ushort4*>(out)[i] = o;
}

// ------------- batched transpose+convert: out[b][c][r] = bf16(in[b][r][c]) -------------
__global__ void k_tconv(const float* __restrict__ in, u16* __restrict__ out, int R, int C) {
  __shared__ float t[32][33];
  long bs = (long)R * C;
  const float* ip = in + blockIdx.z * bs;
  u16* op = out + blockIdx.z * bs;
  int r0 = blockIdx.x * 32, c0 = blockIdx.y * 32;
  int tx = threadIdx.x, ty = threadIdx.y;  // (32,8)
#pragma unroll
  for (int k = 0; k < 4; k++)
    t[ty + k * 8][tx] = ip[(long)(r0 + ty + k * 8) * C + c0 + tx];
  __syncthreads();
#pragma unroll
  for (int k = 0; k < 4; k++)
    op[(long)(c0 + ty + k * 8) * R + r0 + tx] = f2b(t[tx][ty + k * 8]);
}

// ------------- f_src/f_dst (scaled by log2e), c-split with atomic reduce -------------
__global__ void k_fsd2(const u16* __restrict__ WhT, const float* __restrict__ a,
                       float* __restrict__ s, float* __restrict__ d, int dh) {
  int i = blockIdx.x * 256 + threadIdx.x;
  int h = blockIdx.z;
  int c0 = blockIdx.y * 32;
  const u16* w = WhT + ((long)h * dh + c0) * NN + i;
  const float* as = a + (long)h * 2 * dh + c0;
  const float* ad = as + dh;
  float ss = 0.f, dd = 0.f;
#pragma unroll
  for (int c = 0; c < 32; c++) {
    float v = b2f(w[(long)c * NN]);
    ss = fmaf(v, as[c], ss);
    dd = fmaf(v, ad[c], dd);
  }
  atomicAdd(&s[h * NN + i], ss * LOG2E);
  atomicAdd(&d[h * NN + i], dd * LOG2E);
}

// ------------- m[h][i] = lrelu(s[h][i] + max_{j in adj(i)} d[h][j]) -------------
template <int H>
__global__ void k_maxd(const uint32_t* __restrict__ bits, const float* __restrict__ s,
                       const float* __restrict__ d, float* __restrict__ m) {
  int wv = threadIdx.x >> 6, lane = threadIdx.x & 63;
  int row = blockIdx.x * 4 + wv;
  const uint32_t* br = bits + (long)row * 128;
  float mx[H];
#pragma unroll
  for (int h = 0; h < H; h++) mx[h] = -1e30f;
  for (int t = 0; t < 64; t++) {
    int j = t * 64 + lane;
    uint32_t wb = br[j >> 5];
    bool on = (wb >> (j & 31)) & 1u;
#pragma unroll
    for (int h = 0; h < H; h++) {
      float dv = d[h * NN + j];
      mx[h] = (on && dv > mx[h]) ? dv : mx[h];
    }
  }
#pragma unroll
  for (int h = 0; h < H; h++) {
    float v = mx[h];
#pragma unroll
    for (int o = 32; o >= 1; o >>= 1) v = fmaxf(v, __shfl_xor(v, o));
    if (lane == 0) {
      float e = s[h * NN + row] + v;
      m[h * NN + row] = fmaxf(e, 0.2f * e);
    }
  }
}

// ------------- bf16 GEMM C = A @ B given BT, writes CT[n][i] = bf16(C[i][n]) -------------
__global__ __launch_bounds__(256, 2) void k_gemm(const u16* __restrict__ A,
                                                 const u16* __restrict__ BT,
                                                 u16* __restrict__ CT, int K) {
  __shared__ __align__(16) u16 As[128 * 64];
  __shared__ __align__(16) u16 Bs[128 * 64];
  int tid = threadIdx.x;
  int w = tid >> 6, lane = tid & 63;
  int i0 = blockIdx.x * 128, n0 = blockIdx.y * 128;
  int wr = w >> 1, wc = w & 1;
  int l15 = lane & 15, l4 = lane >> 4;

  f32x4 acc[4][4] = {};

  int srow = lane >> 3;
  int sj = ((lane & 7) ^ srow) * 8;  // pre-swizzled source chunk (chunk ^= row&7)

  for (int kt = 0; kt < K / 64; kt++) {
    int k0 = kt * 64;
    __syncthreads();
#pragma unroll
    for (int t = 0; t < 4; t++) {
      int r = w * 32 + t * 8 + srow;
      gload_lds16(A + (long)(i0 + r) * K + k0 + sj, &As[(w * 32 + t * 8) * 64]);
      gload_lds16(BT + (long)(n0 + r) * K + k0 + sj, &Bs[(w * 32 + t * 8) * 64]);
    }
    __syncthreads();
#pragma unroll
    for (int kc = 0; kc < 2; kc++) {
      bf16x8 af[4], bf[4];
#pragma unroll
      for (int mi = 0; mi < 4; mi++) {
        int r = wr * 64 + mi * 16 + l15;
        int ph = (kc * 4 + l4) ^ (r & 7);
        af[mi] = *reinterpret_cast<const bf16x8*>(&As[r * 64 + ph * 8]);
      }
#pragma unroll
      for (int ni = 0; ni < 4; ni++) {
        int r = wc * 64 + ni * 16 + l15;
        int ph = (kc * 4 + l4) ^ (r & 7);
        bf[ni] = *reinterpret_cast<const bf16x8*>(&Bs[r * 64 + ph * 8]);
      }
#pragma unroll
      for (int mi = 0; mi < 4; mi++)
#pragma unroll
        for (int ni = 0; ni < 4; ni++)
          acc[mi][ni] =
              __builtin_amdgcn_mfma_f32_16x16x32_bf16(af[mi], bf[ni], acc[mi][ni], 0, 0, 0);
    }
  }
#pragma unroll
  for (int mi = 0; mi < 4; mi++) {
    int i = i0 + wr * 64 + mi * 16 + l4 * 4;
#pragma unroll
    for (int ni = 0; ni < 4; ni++) {
      int n = n0 + wc * 64 + ni * 16 + l15;
      ushort4 o;
      o.x = f2b(acc[mi][ni][0]);
      o.y = f2b(acc[mi][ni][1]);
      o.z = f2b(acc[mi][ni][2]);
      o.w = f2b(acc[mi][ni][3]);
      *reinterpret_cast<ushort4*>(&CT[(long)n * NN + i]) = o;
    }
  }
}

// ------------- fused masked-softmax-attention @ Wh (col-split 128, double-buffered) -------------
// grid (8 cb, 32 rowblock); colbase = cb*128 (heads are contiguous 256-col spans).
// MODE 0: head = cb>>1, writes hout[i][col] = bf16(elu(att@Wh))
// MODE 1: h = 0, writes xout = xin + elu(att@Wh2), plus bf16 copy
// block: 4 waves x 32 rows x 128 cols; j-loop BK=64, 2-phase dbuf staging, Z in registers.
template <int MODE>
__global__ __launch_bounds__(256, 2) void k_pv(const uint32_t* __restrict__ bits,
                                               const u16* __restrict__ WT,
                                               const float* __restrict__ sA,
                                               const float* __restrict__ dA,
                                               const float* __restrict__ mA,
                                               u16* __restrict__ hout,
                                               const float* __restrict__ xin,
                                               float* __restrict__ xout,
                                               u16* __restrict__ xbout) {
  __shared__ __align__(16) u16 Bs[2][128 * 64];
  int tid = threadIdx.x;
  int w = tid >> 6, lane = tid & 63;
  int cb = blockIdx.x;            // col-block: wgid%8 == cb -> one B-slice per XCD L2
  int i0 = blockIdx.y * 128;
  int h = (MODE == 0) ? (cb >> 1) : 0;

  const u16* Bsrc = WT + (long)cb * 128 * NN;
  const float* dv = dA + (long)h * NN;
  int l15 = lane & 15, l4 = lane >> 4;
  int rbase = i0 + w * 32 + l15;
  float s0 = sA[h * NN + rbase], s1 = sA[h * NN + rbase + 16];
  float m0 = mA[h * NN + rbase], m1 = mA[h * NN + rbase + 16];
  const uint8_t* bb = reinterpret_cast<const uint8_t*>(bits);
  const uint8_t* br0 = bb + (long)rbase * 512;
  const uint8_t* br1 = br0 + 16 * 512;

  f32x4 acc[2][8] = {};
  float zp0 = 0.f, zp1 = 0.f;

  int srow = lane >> 3;
  int sj = ((lane & 7) ^ srow) * 8;   // pre-swizzled source chunk (chunk ^= row&7)

  // stage tile kt into buf b: 128 cols x 64 j (4 rounds x 4 waves x 8 rows)
#define STAGE(b, kt_)                                                            \
  {                                                                              \
    int j0_ = (kt_) * 64;                                                        \
    _Pragma("unroll") for (int t = 0; t < 4; t++) {                              \
      int c = w * 32 + t * 8 + srow;                                             \
      gload_lds16(Bsrc + (long)c * NN + j0_ + sj, &Bs[b][c * 64]);               \
    }                                                                            \
  }

  STAGE(0, 0);
  __syncthreads();

  for (int kt = 0; kt < 64; kt++) {
    int cur = kt & 1;
    if (kt < 63) STAGE(cur ^ 1, kt + 1);   // overlap next-tile loads with compute
    int j0 = kt * 64;
#pragma unroll
    for (int kc = 0; kc < 2; kc++) {
      int jb = j0 + kc * 32 + l4 * 8;
      f32x4 dlo = *reinterpret_cast<const f32x4*>(&dv[jb]);
      f32x4 dhi = *reinterpret_cast<const f32x4*>(&dv[jb + 4]);
      uint32_t b0 = br0[jb >> 3], b1 = br1[jb >> 3];
      bf16x8 a0, a1;
#pragma unroll
      for (int e = 0; e < 8; e++) {
        float dj = (e < 4) ? dlo[e] : dhi[e - 4];
        float v0 = s0 + dj;
        v0 = fmaxf(v0, 0.2f * v0) - m0;          // lrelu - m   (log2 domain)
        float p0 = ((b0 >> e) & 1u) ? exp2f(v0) : 0.f;
        zp0 += p0;
        a0[e] = (__bf16)p0;
        float v1 = s1 + dj;
        v1 = fmaxf(v1, 0.2f * v1) - m1;
        float p1 = ((b1 >> e) & 1u) ? exp2f(v1) : 0.f;
        zp1 += p1;
        a1[e] = (__bf16)p1;
      }
#pragma unroll
      for (int nt = 0; nt < 8; nt++) {
        int c = nt * 16 + l15;
        int ph = (kc * 4 + l4) ^ (c & 7);
        bf16x8 bfr = *reinterpret_cast<const bf16x8*>(&Bs[cur][c * 64 + ph * 8]);
        acc[0][nt] = __builtin_amdgcn_mfma_f32_16x16x32_bf16(a0, bfr, acc[0][nt], 0, 0, 0);
        acc[1][nt] = __builtin_amdgcn_mfma_f32_16x16x32_bf16(a1, bfr, acc[1][nt], 0, 0, 0);
      }
    }
    __syncthreads();   // drains staged loads (vmcnt 0) + protects buf reuse
  }
#undef STAGE

  float z0 = zp0, z1 = zp1;
  z0 += __shfl_xor(z0, 16);
  z0 += __shfl_xor(z0, 32);
  z1 += __shfl_xor(z1, 16);
  z1 += __shfl_xor(z1, 32);

#pragma unroll
  for (int mi = 0; mi < 2; mi++) {
    float zsrc = (mi == 0) ? z0 : z1;
    float zr[4];
#pragma unroll
    for (int r = 0; r < 4; r++) zr[r] = __shfl(zsrc, l4 * 4 + r);
#pragma unroll
    for (int nt = 0; nt < 8; nt++) {
      int col = cb * 128 + nt * 16 + l15;
#pragma unroll
      for (int r = 0; r < 4; r++) {
        int i = i0 + w * 32 + mi * 16 + l4 * 4 + r;
        float val = acc[mi][nt][r] / zr[r];
        float o = val > 0.f ? val : exp2f(val * LOG2E) - 1.f;  // elu
        long idx = (long)i * FF + col;
        if (MODE == 0) {
          hout[idx] = f2b(o);
        } else {
          float xn = xin[idx] + o;
          xout[idx] = xn;
          xbout[idx] = f2b(xn);
        }
      }
    }
  }
}

extern "C" void kernel_launch(void* const* d_in, const int* in_sizes, int n_in,
                              void* d_out, int out_size, void* d_ws, size_t ws_size,
                              hipStream_t stream) {
  const float* x = (const float*)d_in[0];
  const int* adj = (const int*)d_in[1];
  const float* W_heads = (const float*)d_in[2];  // [2][4][1024][256]
  const float* a_heads = (const float*)d_in[3];  // [2][4][512]
  const float* W_out = (const float*)d_in[4];    // [2][1024][1024]
  const float* a_out = (const float*)d_in[5];    // [2][2048]
  float* out = (float*)d_out;

  char* ws = (char*)d_ws;
  uint32_t* bits = (uint32_t*)(ws + 0x0);       // 2 MB
  u16* xb = (u16*)(ws + 0x200000);              // 8 MB  bf16 x / x_new
  u16* WcatT = (u16*)(ws + 0xA00000);           // 4 MB  [2][1024 n][1024 k]
  u16* WoutT = (u16*)(ws + 0xE00000);           // 4 MB
  u16* WhT = (u16*)(ws + 0x1200000);            // 8 MB  [1024][4096] (reused for Wh2)
  u16* hbuf = (u16*)(ws + 0x1A00000);           // 8 MB  h bf16 [4096][1024]
  float* xmid = (float*)(ws + 0x2200000);       // 16 MB x after layer 0
  float* s_h = (float*)(ws + 0x3200000);        // [4][4096]
  float* d_h = (float*)(ws + 0x3210000);
  float* m_h = (float*)(ws + 0x3220000);
  float* s_o = (float*)(ws + 0x3230000);        // [4096]
  float* d_o = (float*)(ws + 0x3234000);
  float* m_o = (float*)(ws + 0x3238000);

  k_pack<<<65536, 256, 0, stream>>>(adj, bits);
  k_cvt<<<4096, 256, 0, stream>>>(x, xb, NN * FF / 4);
  k_tconv<<<dim3(32, 8, 8), dim3(32, 8), 0, stream>>>(W_heads, WcatT, 1024, 256);
  k_tconv<<<dim3(32, 32, 2), dim3(32, 8), 0, stream>>>(W_out, WoutT, 1024, 1024);

  for (int l = 0; l < 2; l++) {
    // zero the s/d/m stats region (s_h,d_h,m_h,s_o,d_o,m_o) for this layer
    hipMemsetAsync(ws + 0x3200000, 0, 0x3C000, stream);
    k_gemm<<<dim3(32, 8), 256, 0, stream>>>(xb, WcatT + l * 1048576, WhT, FF);
    k_fsd2<<<dim3(16, 8, 4), 256, 0, stream>>>(WhT, a_heads + l * 2048, s_h, d_h, 256);
    k_maxd<4><<<1024, 256, 0, stream>>>(bits, s_h, d_h, m_h);
    k_pv<0><<<dim3(8, 32), 256, 0, stream>>>(bits, WhT, s_h, d_h, m_h, hbuf, nullptr,
                                             nullptr, nullptr);
    k_gemm<<<dim3(32, 8), 256, 0, stream>>>(hbuf, WoutT + l * 1048576, WhT, FF);
    k_fsd2<<<dim3(16, 32, 1), 256, 0, stream>>>(WhT, a_out + l * 2048, s_o, d_o, 1024);
    k_maxd<1><<<1024, 256, 0, stream>>>(bits, s_o, d_o, m_o);
    k_pv<1><<<dim3(8, 32), 256, 0, stream>>>(bits, WhT, s_o, d_o, m_o, nullptr,
                                             l ? xmid : x, l ? out : xmid, xb);
  }
}

// Round 5
// 660.457 us; speedup vs baseline: 2.6369x; 1.4108x over previous
//
#include <hip/hip_runtime.h>
#include <hip/hip_bf16.h>
#include <stdint.h>

// N=4096, NFEAT=1024, NHID=256, NHEADS=4, NCLASS=1024, NLAYERS=2
#define NN 4096
#define FF 1024
#define LOG2E 1.44269504088896340736f

typedef unsigned short u16;
typedef float f32x4 __attribute__((ext_vector_type(4)));
typedef __bf16 bf16x8 __attribute__((ext_vector_type(8)));

typedef __attribute__((address_space(1))) void gvoid_t;
typedef __attribute__((address_space(3))) void lvoid_t;

__device__ __forceinline__ u16 f2b(float f) {
  __bf16 b = (__bf16)f;
  return __builtin_bit_cast(u16, b);
}
__device__ __forceinline__ float b2f(u16 u) {
  return (float)__builtin_bit_cast(__bf16, u);
}
__device__ __forceinline__ void gload_lds16(const void* g, void* l) {
  __builtin_amdgcn_global_load_lds((gvoid_t*)g, (lvoid_t*)l, 16, 0, 0);
}

// ---------------- adjacency -> bitmask [4096][128] u32 ----------------
__global__ void k_pack(const int* __restrict__ adj, uint32_t* __restrict__ bits) {
  int gw = (blockIdx.x * 256 + threadIdx.x) >> 6;
  int lane = threadIdx.x & 63;
  int row = gw >> 6;
  int j0 = (gw & 63) << 6;
  int a = adj[(long)row * NN + j0 + lane];
  unsigned long long m = __ballot(a != 0);
  if (lane == 0)
    *reinterpret_cast<unsigned long long*>(&bits[row * 128 + (j0 >> 5)]) = m;
}

// ---------------- f32 -> bf16 convert (vectorized) ----------------
__global__ void k_cvt(const float* __restrict__ in, u16* __restrict__ out, int n4) {
  int i = blockIdx.x * 256 + threadIdx.x;
  if (i >= n4) return;
  float4 v = reinterpret_cast<const float4*>(in)[i];
  ushort4 o;
  o.x = f2b(v.x); o.y = f2b(v.y); o.z = f2b(v.z); o.w = f2b(v.w);
  reinterpret_cast<ushort4*>(out)[i] = o;
}

// ------------- batched transpose+convert: out[b][c][r] = bf16(in[b][r][c]) -------------
__global__ void k_tconv(const float* __restrict__ in, u16* __restrict__ out, int R, int C) {
  __shared__ float t[32][33];
  long bs = (long)R * C;
  const float* ip = in + blockIdx.z * bs;
  u16* op = out + blockIdx.z * bs;
  int r0 = blockIdx.x * 32, c0 = blockIdx.y * 32;
  int tx = threadIdx.x, ty = threadIdx.y;  // (32,8)
#pragma unroll
  for (int k = 0; k < 4; k++)
    t[ty + k * 8][tx] = ip[(long)(r0 + ty + k * 8) * C + c0 + tx];
  __syncthreads();
#pragma unroll
  for (int k = 0; k < 4; k++)
    op[(long)(c0 + ty + k * 8) * R + r0 + tx] = f2b(t[tx][ty + k * 8]);
}

// ------------- f_src/f_dst (scaled by log2e), c-split with atomic reduce -------------
__global__ void k_fsd2(const u16* __restrict__ WhT, const float* __restrict__ a,
                       float* __restrict__ s, float* __restrict__ d, int dh) {
  int i = blockIdx.x * 256 + threadIdx.x;
  int h = blockIdx.z;
  int c0 = blockIdx.y * 32;
  const u16* w = WhT + ((long)h * dh + c0) * NN + i;
  const float* as = a + (long)h * 2 * dh + c0;
  const float* ad = as + dh;
  float ss = 0.f, dd = 0.f;
#pragma unroll
  for (int c = 0; c < 32; c++) {
    float v = b2f(w[(long)c * NN]);
    ss = fmaf(v, as[c], ss);
    dd = fmaf(v, ad[c], dd);
  }
  atomicAdd(&s[h * NN + i], ss * LOG2E);
  atomicAdd(&d[h * NN + i], dd * LOG2E);
}

// ------------- m[h][i] = lrelu(s[h][i] + max_{j in adj(i)} d[h][j]) -------------
template <int H>
__global__ void k_maxd(const uint32_t* __restrict__ bits, const float* __restrict__ s,
                       const float* __restrict__ d, float* __restrict__ m) {
  int wv = threadIdx.x >> 6, lane = threadIdx.x & 63;
  int row = blockIdx.x * 4 + wv;
  const uint32_t* br = bits + (long)row * 128;
  float mx[H];
#pragma unroll
  for (int h = 0; h < H; h++) mx[h] = -1e30f;
  for (int t = 0; t < 64; t++) {
    int j = t * 64 + lane;
    uint32_t wb = br[j >> 5];
    bool on = (wb >> (j & 31)) & 1u;
#pragma unroll
    for (int h = 0; h < H; h++) {
      float dv = d[h * NN + j];
      mx[h] = (on && dv > mx[h]) ? dv : mx[h];
    }
  }
#pragma unroll
  for (int h = 0; h < H; h++) {
    float v = mx[h];
#pragma unroll
    for (int o = 32; o >= 1; o >>= 1) v = fmaxf(v, __shfl_xor(v, o));
    if (lane == 0) {
      float e = s[h * NN + row] + v;
      m[h * NN + row] = fmaxf(e, 0.2f * e);
    }
  }
}

// ------------- bf16 GEMM C = A @ B given BT, writes CT[n][i] = bf16(C[i][n]) -------------
__global__ __launch_bounds__(256, 2) void k_gemm(const u16* __restrict__ A,
                                                 const u16* __restrict__ BT,
                                                 u16* __restrict__ CT, int K) {
  __shared__ __align__(16) u16 As[128 * 64];
  __shared__ __align__(16) u16 Bs[128 * 64];
  int tid = threadIdx.x;
  int w = tid >> 6, lane = tid & 63;
  int i0 = blockIdx.x * 128, n0 = blockIdx.y * 128;
  int wr = w >> 1, wc = w & 1;
  int l15 = lane & 15, l4 = lane >> 4;

  f32x4 acc[4][4] = {};

  int srow = lane >> 3;
  int sj = ((lane & 7) ^ srow) * 8;  // pre-swizzled source chunk (chunk ^= row&7)

  for (int kt = 0; kt < K / 64; kt++) {
    int k0 = kt * 64;
    __syncthreads();
#pragma unroll
    for (int t = 0; t < 4; t++) {
      int r = w * 32 + t * 8 + srow;
      gload_lds16(A + (long)(i0 + r) * K + k0 + sj, &As[(w * 32 + t * 8) * 64]);
      gload_lds16(BT + (long)(n0 + r) * K + k0 + sj, &Bs[(w * 32 + t * 8) * 64]);
    }
    __syncthreads();
#pragma unroll
    for (int kc = 0; kc < 2; kc++) {
      bf16x8 af[4], bf[4];
#pragma unroll
      for (int mi = 0; mi < 4; mi++) {
        int r = wr * 64 + mi * 16 + l15;
        int ph = (kc * 4 + l4) ^ (r & 7);
        af[mi] = *reinterpret_cast<const bf16x8*>(&As[r * 64 + ph * 8]);
      }
#pragma unroll
      for (int ni = 0; ni < 4; ni++) {
        int r = wc * 64 + ni * 16 + l15;
        int ph = (kc * 4 + l4) ^ (r & 7);
        bf[ni] = *reinterpret_cast<const bf16x8*>(&Bs[r * 64 + ph * 8]);
      }
#pragma unroll
      for (int mi = 0; mi < 4; mi++)
#pragma unroll
        for (int ni = 0; ni < 4; ni++)
          acc[mi][ni] =
              __builtin_amdgcn_mfma_f32_16x16x32_bf16(af[mi], bf[ni], acc[mi][ni], 0, 0, 0);
    }
  }
#pragma unroll
  for (int mi = 0; mi < 4; mi++) {
    int i = i0 + wr * 64 + mi * 16 + l4 * 4;
#pragma unroll
    for (int ni = 0; ni < 4; ni++) {
      int n = n0 + wc * 64 + ni * 16 + l15;
      ushort4 o;
      o.x = f2b(acc[mi][ni][0]);
      o.y = f2b(acc[mi][ni][1]);
      o.z = f2b(acc[mi][ni][2]);
      o.w = f2b(acc[mi][ni][3]);
      *reinterpret_cast<ushort4*>(&CT[(long)n * NN + i]) = o;
    }
  }
}

// ------------- fused masked-softmax-attention @ Wh (col-split 128, dbuf + d-prefetch) -------------
// grid (8 cb, 64 rowblock); colbase = cb*128. Block = 4 waves, wave = 16 rows x 128 cols.
// MODE 0: head = cb>>1, writes hout[i][col] = bf16(elu(att@Wh))
// MODE 1: h = 0, writes xout = xin + elu(att@Wh2), plus bf16 copy
template <int MODE>
__global__ __launch_bounds__(256, 2) void k_pv(const uint32_t* __restrict__ bits,
                                               const u16* __restrict__ WT,
                                               const float* __restrict__ sA,
                                               const float* __restrict__ dA,
                                               const float* __restrict__ mA,
                                               u16* __restrict__ hout,
                                               const float* __restrict__ xin,
                                               float* __restrict__ xout,
                                               u16* __restrict__ xbout) {
  __shared__ __align__(16) u16 Bs[2][128 * 64];
  int tid = threadIdx.x;
  int w = tid >> 6, lane = tid & 63;
  int cb = blockIdx.x;            // col-block: wgid%8 == cb -> one B-slice per XCD L2
  int i0 = blockIdx.y * 64;
  int h = (MODE == 0) ? (cb >> 1) : 0;

  const u16* Bsrc = WT + (long)cb * 128 * NN;
  const float* dv = dA + (long)h * NN;
  int l15 = lane & 15, l4 = lane >> 4;
  int rbase = i0 + w * 16 + l15;  // wave owns one 16-row group
  float s0 = sA[h * NN + rbase];
  float m0 = mA[h * NN + rbase];
  float Ac = s0 - m0;             // lrelu(s+d)-m = fmax(Ac+d, fma(0.2,d,Bc))
  float Bc = 0.2f * s0 - m0;
  const uint8_t* br0 = reinterpret_cast<const uint8_t*>(bits) + (long)rbase * 512;

  f32x4 acc[8] = {};
  float zp0 = 0.f;

  int srow = lane >> 3;
  int sj = ((lane & 7) ^ srow) * 8;   // pre-swizzled source chunk (chunk ^= row&7)

  // stage tile kt into buf b: 128 cols x 64 j (4 waves x 4 rounds x 8 rows)
#define STAGE(b, kt_)                                                            \
  {                                                                              \
    int j0_ = (kt_) * 64;                                                        \
    _Pragma("unroll") for (int t = 0; t < 4; t++) {                              \
      int c = w * 32 + t * 8 + srow;                                             \
      gload_lds16(Bsrc + (long)c * NN + j0_ + sj, &Bs[b][c * 64]);               \
    }                                                                            \
  }
  // prefetch d-vector + mask byte for tile kt_ into p-regs (removes L2 latency from chain)
#define PREF(kt_)                                                                \
  {                                                                              \
    int jb_ = (kt_) * 64 + l4 * 8;                                               \
    plo[0] = *reinterpret_cast<const f32x4*>(&dv[jb_]);                          \
    phi[0] = *reinterpret_cast<const f32x4*>(&dv[jb_ + 4]);                      \
    plo[1] = *reinterpret_cast<const f32x4*>(&dv[jb_ + 32]);                     \
    phi[1] = *reinterpret_cast<const f32x4*>(&dv[jb_ + 36]);                     \
    pmb[0] = br0[jb_ >> 3];                                                      \
    pmb[1] = br0[(jb_ >> 3) + 4];                                                \
  }

  f32x4 plo[2], phi[2];
  uint32_t pmb[2];
  PREF(0);
  STAGE(0, 0);
  __syncthreads();

  for (int kt = 0; kt < 64; kt++) {
    int cur = kt & 1;
    if (kt < 63) STAGE(cur ^ 1, kt + 1);   // overlap next B-tile loads with compute
    f32x4 clo[2], chi[2];
    uint32_t cmb[2];
#pragma unroll
    for (int kc = 0; kc < 2; kc++) { clo[kc] = plo[kc]; chi[kc] = phi[kc]; cmb[kc] = pmb[kc]; }
    if (kt < 63) PREF(kt + 1);             // overlap next d/mask loads with compute
#pragma unroll
    for (int kc = 0; kc < 2; kc++) {
      uint32_t b0 = cmb[kc];
      bf16x8 a0;
#pragma unroll
      for (int e = 0; e < 8; e++) {
        float dj = (e < 4) ? clo[kc][e] : chi[kc][e - 4];
        float v0 = fmaxf(Ac + dj, fmaf(0.2f, dj, Bc));   // lrelu - m (log2 domain)
        float p0 = ((b0 >> e) & 1u) ? exp2f(v0) : 0.f;
        zp0 += p0;
        a0[e] = (__bf16)p0;
      }
#pragma unroll
      for (int nt = 0; nt < 8; nt++) {
        int c = nt * 16 + l15;
        int ph = (kc * 4 + l4) ^ (c & 7);
        bf16x8 bfr = *reinterpret_cast<const bf16x8*>(&Bs[cur][c * 64 + ph * 8]);
        acc[nt] = __builtin_amdgcn_mfma_f32_16x16x32_bf16(a0, bfr, acc[nt], 0, 0, 0);
      }
    }
    __syncthreads();   // drains staged loads (vmcnt 0) + protects buf reuse
  }
#undef STAGE
#undef PREF

  float z0 = zp0;
  z0 += __shfl_xor(z0, 16);
  z0 += __shfl_xor(z0, 32);

  float zr[4];
#pragma unroll
  for (int r = 0; r < 4; r++) zr[r] = __shfl(z0, l4 * 4 + r);
#pragma unroll
  for (int nt = 0; nt < 8; nt++) {
    int col = cb * 128 + nt * 16 + l15;
#pragma unroll
    for (int r = 0; r < 4; r++) {
      int i = i0 + w * 16 + l4 * 4 + r;
      float val = acc[nt][r] / zr[r];
      float o = val > 0.f ? val : exp2f(val * LOG2E) - 1.f;  // elu
      long idx = (long)i * FF + col;
      if (MODE == 0) {
        hout[idx] = f2b(o);
      } else {
        float xn = xin[idx] + o;
        xout[idx] = xn;
        xbout[idx] = f2b(xn);
      }
    }
  }
}

extern "C" void kernel_launch(void* const* d_in, const int* in_sizes, int n_in,
                              void* d_out, int out_size, void* d_ws, size_t ws_size,
                              hipStream_t stream) {
  const float* x = (const float*)d_in[0];
  const int* adj = (const int*)d_in[1];
  const float* W_heads = (const float*)d_in[2];  // [2][4][1024][256]
  const float* a_heads = (const float*)d_in[3];  // [2][4][512]
  const float* W_out = (const float*)d_in[4];    // [2][1024][1024]
  const float* a_out = (const float*)d_in[5];    // [2][2048]
  float* out = (float*)d_out;

  char* ws = (char*)d_ws;
  uint32_t* bits = (uint32_t*)(ws + 0x0);       // 2 MB
  u16* xb = (u16*)(ws + 0x200000);              // 8 MB  bf16 x / x_new
  u16* WcatT = (u16*)(ws + 0xA00000);           // 4 MB  [2][1024 n][1024 k]
  u16* WoutT = (u16*)(ws + 0xE00000);           // 4 MB
  u16* WhT = (u16*)(ws + 0x1200000);            // 8 MB  [1024][4096] (reused for Wh2)
  u16* hbuf = (u16*)(ws + 0x1A00000);           // 8 MB  h bf16 [4096][1024]
  float* xmid = (float*)(ws + 0x2200000);       // 16 MB x after layer 0
  float* s_h = (float*)(ws + 0x3200000);        // [4][4096]
  float* d_h = (float*)(ws + 0x3210000);
  float* m_h = (float*)(ws + 0x3220000);
  float* s_o = (float*)(ws + 0x3230000);        // [4096]
  float* d_o = (float*)(ws + 0x3234000);
  float* m_o = (float*)(ws + 0x3238000);

  k_pack<<<65536, 256, 0, stream>>>(adj, bits);
  k_cvt<<<4096, 256, 0, stream>>>(x, xb, NN * FF / 4);
  k_tconv<<<dim3(32, 8, 8), dim3(32, 8), 0, stream>>>(W_heads, WcatT, 1024, 256);
  k_tconv<<<dim3(32, 32, 2), dim3(32, 8), 0, stream>>>(W_out, WoutT, 1024, 1024);

  for (int l = 0; l < 2; l++) {
    // zero the s/d/m stats region (s_h,d_h,m_h,s_o,d_o,m_o) for this layer
    hipMemsetAsync(ws + 0x3200000, 0, 0x3C000, stream);
    k_gemm<<<dim3(32, 8), 256, 0, stream>>>(xb, WcatT + l * 1048576, WhT, FF);
    k_fsd2<<<dim3(16, 8, 4), 256, 0, stream>>>(WhT, a_heads + l * 2048, s_h, d_h, 256);
    k_maxd<4><<<1024, 256, 0, stream>>>(bits, s_h, d_h, m_h);
    k_pv<0><<<dim3(8, 64), 256, 0, stream>>>(bits, WhT, s_h, d_h, m_h, hbuf, nullptr,
                                             nullptr, nullptr);
    k_gemm<<<dim3(32, 8), 256, 0, stream>>>(hbuf, WoutT + l * 1048576, WhT, FF);
    k_fsd2<<<dim3(16, 32, 1), 256, 0, stream>>>(WhT, a_out + l * 2048, s_o, d_o, 1024);
    k_maxd<1><<<1024, 256, 0, stream>>>(bits, s_o, d_o, m_o);
    k_pv<1><<<dim3(8, 64), 256, 0, stream>>>(bits, WhT, s_o, d_o, m_o, nullptr,
                                             l ? xmid : x, l ? out : xmid, xb);
  }
}

// Round 6
// 574.364 us; speedup vs baseline: 3.0321x; 1.1499x over previous
//
#include <hip/hip_runtime.h>
#include <hip/hip_bf16.h>
#include <stdint.h>

// N=4096, NFEAT=1024, NHID=256, NHEADS=4, NCLASS=1024, NLAYERS=2
#define NN 4096
#define FF 1024
#define LOG2E 1.44269504088896340736f

typedef unsigned short u16;
typedef float f32x4 __attribute__((ext_vector_type(4)));
typedef __bf16 bf16x8 __attribute__((ext_vector_type(8)));
typedef u16 u16x8 __attribute__((ext_vector_type(8)));

typedef __attribute__((address_space(1))) void gvoid_t;
typedef __attribute__((address_space(3))) void lvoid_t;

__device__ __forceinline__ u16 f2b(float f) {
  __bf16 b = (__bf16)f;
  return __builtin_bit_cast(u16, b);
}
__device__ __forceinline__ float b2f(u16 u) {
  return (float)__builtin_bit_cast(__bf16, u);
}
__device__ __forceinline__ void gload_lds16(const void* g, void* l) {
  __builtin_amdgcn_global_load_lds((gvoid_t*)g, (lvoid_t*)l, 16, 0, 0);
}

// ---------------- adjacency -> bitmask [4096][128] u32 ----------------
__global__ void k_pack(const int* __restrict__ adj, uint32_t* __restrict__ bits) {
  int gw = (blockIdx.x * 256 + threadIdx.x) >> 6;
  int lane = threadIdx.x & 63;
  int row = gw >> 6;
  int j0 = (gw & 63) << 6;
  int a = adj[(long)row * NN + j0 + lane];
  unsigned long long m = __ballot(a != 0);
  if (lane == 0)
    *reinterpret_cast<unsigned long long*>(&bits[row * 128 + (j0 >> 5)]) = m;
}

// ---------------- f32 -> bf16 convert (vectorized) ----------------
__global__ void k_cvt(const float* __restrict__ in, u16* __restrict__ out, int n4) {
  int i = blockIdx.x * 256 + threadIdx.x;
  if (i >= n4) return;
  float4 v = reinterpret_cast<const float4*>(in)[i];
  ushort4 o;
  o.x = f2b(v.x); o.y = f2b(v.y); o.z = f2b(v.z); o.w = f2b(v.w);
  reinterpret_cast<ushort4*>(out)[i] = o;
}

// ------------- batched transpose+convert: out[b][c][r] = bf16(in[b][r][c]) -------------
__global__ void k_tconv(const float* __restrict__ in, u16* __restrict__ out, int R, int C) {
  __shared__ float t[32][33];
  long bs = (long)R * C;
  const float* ip = in + blockIdx.z * bs;
  u16* op = out + blockIdx.z * bs;
  int r0 = blockIdx.x * 32, c0 = blockIdx.y * 32;
  int tx = threadIdx.x, ty = threadIdx.y;  // (32,8)
#pragma unroll
  for (int k = 0; k < 4; k++)
    t[ty + k * 8][tx] = ip[(long)(r0 + ty + k * 8) * C + c0 + tx];
  __syncthreads();
#pragma unroll
  for (int k = 0; k < 4; k++)
    op[(long)(c0 + ty + k * 8) * R + r0 + tx] = f2b(t[tx][ty + k * 8]);
}

// ------------- f_src/f_dst (scaled by log2e), c-split with atomic reduce -------------
__global__ void k_fsd2(const u16* __restrict__ WhT, const float* __restrict__ a,
                       float* __restrict__ s, float* __restrict__ d, int dh) {
  int i = blockIdx.x * 256 + threadIdx.x;
  int h = blockIdx.z;
  int c0 = blockIdx.y * 32;
  const u16* w = WhT + ((long)h * dh + c0) * NN + i;
  const float* as = a + (long)h * 2 * dh + c0;
  const float* ad = as + dh;
  float ss = 0.f, dd = 0.f;
#pragma unroll
  for (int c = 0; c < 32; c++) {
    float v = b2f(w[(long)c * NN]);
    ss = fmaf(v, as[c], ss);
    dd = fmaf(v, ad[c], dd);
  }
  atomicAdd(&s[h * NN + i], ss * LOG2E);
  atomicAdd(&d[h * NN + i], dd * LOG2E);
}

// ------------- m[h][i] = lrelu(s[h][i] + max_{j in adj(i)} d[h][j]) -------------
template <int H>
__global__ void k_maxd(const uint32_t* __restrict__ bits, const float* __restrict__ s,
                       const float* __restrict__ d, float* __restrict__ m) {
  int wv = threadIdx.x >> 6, lane = threadIdx.x & 63;
  int row = blockIdx.x * 4 + wv;
  const uint32_t* br = bits + (long)row * 128;
  float mx[H];
#pragma unroll
  for (int h = 0; h < H; h++) mx[h] = -1e30f;
  for (int t = 0; t < 64; t++) {
    int j = t * 64 + lane;
    uint32_t wb = br[j >> 5];
    bool on = (wb >> (j & 31)) & 1u;
#pragma unroll
    for (int h = 0; h < H; h++) {
      float dv = d[h * NN + j];
      mx[h] = (on && dv > mx[h]) ? dv : mx[h];
    }
  }
#pragma unroll
  for (int h = 0; h < H; h++) {
    float v = mx[h];
#pragma unroll
    for (int o = 32; o >= 1; o >>= 1) v = fmaxf(v, __shfl_xor(v, o));
    if (lane == 0) {
      float e = s[h * NN + row] + v;
      m[h * NN + row] = fmaxf(e, 0.2f * e);
    }
  }
}

// ------------- bf16 GEMM C = A @ B given BT, writes CT[n][i] = bf16(C[i][n]) -------------
__global__ __launch_bounds__(256, 2) void k_gemm(const u16* __restrict__ A,
                                                 const u16* __restrict__ BT,
                                                 u16* __restrict__ CT, int K) {
  __shared__ __align__(16) u16 As[128 * 64];
  __shared__ __align__(16) u16 Bs[128 * 64];
  int tid = threadIdx.x;
  int w = tid >> 6, lane = tid & 63;
  int i0 = blockIdx.x * 128, n0 = blockIdx.y * 128;
  int wr = w >> 1, wc = w & 1;
  int l15 = lane & 15, l4 = lane >> 4;

  f32x4 acc[4][4] = {};

  int srow = lane >> 3;
  int sj = ((lane & 7) ^ srow) * 8;  // pre-swizzled source chunk (chunk ^= row&7)

  for (int kt = 0; kt < K / 64; kt++) {
    int k0 = kt * 64;
    __syncthreads();
#pragma unroll
    for (int t = 0; t < 4; t++) {
      int r = w * 32 + t * 8 + srow;
      gload_lds16(A + (long)(i0 + r) * K + k0 + sj, &As[(w * 32 + t * 8) * 64]);
      gload_lds16(BT + (long)(n0 + r) * K + k0 + sj, &Bs[(w * 32 + t * 8) * 64]);
    }
    __syncthreads();
#pragma unroll
    for (int kc = 0; kc < 2; kc++) {
      bf16x8 af[4], bf[4];
#pragma unroll
      for (int mi = 0; mi < 4; mi++) {
        int r = wr * 64 + mi * 16 + l15;
        int ph = (kc * 4 + l4) ^ (r & 7);
        af[mi] = *reinterpret_cast<const bf16x8*>(&As[r * 64 + ph * 8]);
      }
#pragma unroll
      for (int ni = 0; ni < 4; ni++) {
        int r = wc * 64 + ni * 16 + l15;
        int ph = (kc * 4 + l4) ^ (r & 7);
        bf[ni] = *reinterpret_cast<const bf16x8*>(&Bs[r * 64 + ph * 8]);
      }
#pragma unroll
      for (int mi = 0; mi < 4; mi++)
#pragma unroll
        for (int ni = 0; ni < 4; ni++)
          acc[mi][ni] =
              __builtin_amdgcn_mfma_f32_16x16x32_bf16(af[mi], bf[ni], acc[mi][ni], 0, 0, 0);
    }
  }
#pragma unroll
  for (int mi = 0; mi < 4; mi++) {
    int i = i0 + wr * 64 + mi * 16 + l4 * 4;
#pragma unroll
    for (int ni = 0; ni < 4; ni++) {
      int n = n0 + wc * 64 + ni * 16 + l15;
      ushort4 o;
      o.x = f2b(acc[mi][ni][0]);
      o.y = f2b(acc[mi][ni][1]);
      o.z = f2b(acc[mi][ni][2]);
      o.w = f2b(acc[mi][ni][3]);
      *reinterpret_cast<ushort4*>(&CT[(long)n * NN + i]) = o;
    }
  }
}

// ------------- P materialization: P[h][i][j] = bf16(exp2(lrelu(s+d)-m)) masked; Z[h][i] = row-sum -------------
// grid (NN/4, H); block 256 = 4 waves; wave = one row; lane covers 8 j per pass, 8 passes.
__global__ void k_pgen(const uint32_t* __restrict__ bits, const float* __restrict__ sA,
                       const float* __restrict__ dA, const float* __restrict__ mA,
                       u16* __restrict__ P, float* __restrict__ Z) {
  int wv = threadIdx.x >> 6, lane = threadIdx.x & 63;
  int row = blockIdx.x * 4 + wv;
  int h = blockIdx.y;
  const float* dv = dA + (long)h * NN;
  float s0 = sA[h * NN + row], m0 = mA[h * NN + row];
  float Ac = s0 - m0;             // lrelu(s+d)-m = fmax(Ac+d, fma(0.2,d,Bc))
  float Bc = 0.2f * s0 - m0;
  const uint8_t* br = reinterpret_cast<const uint8_t*>(bits) + (long)row * 512;
  u16* prow = P + (long)h * NN * NN + (long)row * NN;
  float zp = 0.f;
#pragma unroll
  for (int pass = 0; pass < 8; pass++) {
    int j = pass * 512 + lane * 8;
    f32x4 dlo = *reinterpret_cast<const f32x4*>(&dv[j]);
    f32x4 dhi = *reinterpret_cast<const f32x4*>(&dv[j + 4]);
    uint32_t mb = br[j >> 3];
    u16x8 o;
#pragma unroll
    for (int e = 0; e < 8; e++) {
      float dj = (e < 4) ? dlo[e] : dhi[e - 4];
      float v = fmaxf(Ac + dj, fmaf(0.2f, dj, Bc));
      float p = ((mb >> e) & 1u) ? exp2f(v) : 0.f;
      zp += p;
      o[e] = f2b(p);
    }
    *reinterpret_cast<u16x8*>(&prow[j]) = o;
  }
#pragma unroll
  for (int off = 32; off >= 1; off >>= 1) zp += __shfl_xor(zp, off);
  if (lane == 0) Z[h * NN + row] = zp;
}

// ------------- PV GEMM: C[i][n] = epilogue(sum_j P[h][i][j] * Wh[j][n] / Z[i]) -------------
// 64x128 tile, grid (64 rowblk, 8 colblk) = 512 blocks (2/CU, all co-resident; wgid%8=rowblk%8
// keeps both col-blocks of a head's A-slab on one XCD L2). 4 waves 2x2, wave = 32x64.
// MODE 0: h = n0>>8, writes hout[i][n] = bf16(elu(.)); MODE 1: h=0, xout = xin + elu(.), + bf16 copy.
template <int MODE>
__global__ __launch_bounds__(256, 2) void k_pvg(const u16* __restrict__ P,
                                                const u16* __restrict__ BT,
                                                const float* __restrict__ Z,
                                                u16* __restrict__ hout,
                                                const float* __restrict__ xin,
                                                float* __restrict__ xout,
                                                u16* __restrict__ xbout) {
  __shared__ __align__(16) u16 As[64 * 64];
  __shared__ __align__(16) u16 Bs[128 * 64];
  int tid = threadIdx.x;
  int w = tid >> 6, lane = tid & 63;
  int i0 = blockIdx.x * 64, n0 = blockIdx.y * 128;
  int h = (MODE == 0) ? (n0 >> 8) : 0;
  const u16* A = P + (long)h * NN * NN;
  const float* Zr = Z + (MODE == 0 ? h * NN : 0);
  int wr = w >> 1, wc = w & 1;
  int l15 = lane & 15, l4 = lane >> 4;

  f32x4 acc[2][4] = {};

  int srow = lane >> 3;
  int sj = ((lane & 7) ^ srow) * 8;  // pre-swizzled source chunk (chunk ^= row&7)

  for (int kt = 0; kt < NN / 64; kt++) {
    int k0 = kt * 64;
    __syncthreads();
#pragma unroll
    for (int t = 0; t < 2; t++) {
      int r = w * 16 + t * 8 + srow;
      gload_lds16(A + (long)(i0 + r) * NN + k0 + sj, &As[(w * 16 + t * 8) * 64]);
    }
#pragma unroll
    for (int t = 0; t < 4; t++) {
      int r = w * 32 + t * 8 + srow;
      gload_lds16(BT + (long)(n0 + r) * NN + k0 + sj, &Bs[(w * 32 + t * 8) * 64]);
    }
    __syncthreads();
#pragma unroll
    for (int kc = 0; kc < 2; kc++) {
      bf16x8 af[2], bf[4];
#pragma unroll
      for (int mi = 0; mi < 2; mi++) {
        int r = wr * 32 + mi * 16 + l15;
        int ph = (kc * 4 + l4) ^ (r & 7);
        af[mi] = *reinterpret_cast<const bf16x8*>(&As[r * 64 + ph * 8]);
      }
#pragma unroll
      for (int ni = 0; ni < 4; ni++) {
        int r = wc * 64 + ni * 16 + l15;
        int ph = (kc * 4 + l4) ^ (r & 7);
        bf[ni] = *reinterpret_cast<const bf16x8*>(&Bs[r * 64 + ph * 8]);
      }
#pragma unroll
      for (int mi = 0; mi < 2; mi++)
#pragma unroll
        for (int ni = 0; ni < 4; ni++)
          acc[mi][ni] =
              __builtin_amdgcn_mfma_f32_16x16x32_bf16(af[mi], bf[ni], acc[mi][ni], 0, 0, 0);
    }
  }
#pragma unroll
  for (int mi = 0; mi < 2; mi++) {
#pragma unroll
    for (int r = 0; r < 4; r++) {
      int i = i0 + wr * 32 + mi * 16 + l4 * 4 + r;
      float zi = Zr[i];
#pragma unroll
      for (int ni = 0; ni < 4; ni++) {
        int col = n0 + wc * 64 + ni * 16 + l15;
        float val = acc[mi][ni][r] / zi;
        float o = val > 0.f ? val : exp2f(val * LOG2E) - 1.f;  // elu
        long idx = (long)i * FF + col;
        if (MODE == 0) {
          hout[idx] = f2b(o);
        } else {
          float xn = xin[idx] + o;
          xout[idx] = xn;
          xbout[idx] = f2b(xn);
        }
      }
    }
  }
}

// ------------- fallback fused k_pv (round-5 version) if ws too small for P -------------
template <int MODE>
__global__ __launch_bounds__(256, 2) void k_pv(const uint32_t* __restrict__ bits,
                                               const u16* __restrict__ WT,
                                               const float* __restrict__ sA,
                                               const float* __restrict__ dA,
                                               const float* __restrict__ mA,
                                               u16* __restrict__ hout,
                                               const float* __restrict__ xin,
                                               float* __restrict__ xout,
                                               u16* __restrict__ xbout) {
  __shared__ __align__(16) u16 Bs[2][128 * 64];
  int tid = threadIdx.x;
  int w = tid >> 6, lane = tid & 63;
  int cb = blockIdx.x;
  int i0 = blockIdx.y * 64;
  int h = (MODE == 0) ? (cb >> 1) : 0;

  const u16* Bsrc = WT + (long)cb * 128 * NN;
  const float* dv = dA + (long)h * NN;
  int l15 = lane & 15, l4 = lane >> 4;
  int rbase = i0 + w * 16 + l15;
  float s0 = sA[h * NN + rbase];
  float m0 = mA[h * NN + rbase];
  float Ac = s0 - m0;
  float Bc = 0.2f * s0 - m0;
  const uint8_t* br0 = reinterpret_cast<const uint8_t*>(bits) + (long)rbase * 512;

  f32x4 acc[8] = {};
  float zp0 = 0.f;

  int srow = lane >> 3;
  int sj = ((lane & 7) ^ srow) * 8;

#define STAGE(b, kt_)                                                            \
  {                                                                              \
    int j0_ = (kt_) * 64;                                                        \
    _Pragma("unroll") for (int t = 0; t < 4; t++) {                              \
      int c = w * 32 + t * 8 + srow;                                             \
      gload_lds16(Bsrc + (long)c * NN + j0_ + sj, &Bs[b][c * 64]);               \
    }                                                                            \
  }
#define PREF(kt_)                                                                \
  {                                                                              \
    int jb_ = (kt_) * 64 + l4 * 8;                                               \
    plo[0] = *reinterpret_cast<const f32x4*>(&dv[jb_]);                          \
    phi[0] = *reinterpret_cast<const f32x4*>(&dv[jb_ + 4]);                      \
    plo[1] = *reinterpret_cast<const f32x4*>(&dv[jb_ + 32]);                     \
    phi[1] = *reinterpret_cast<const f32x4*>(&dv[jb_ + 36]);                     \
    pmb[0] = br0[jb_ >> 3];                                                      \
    pmb[1] = br0[(jb_ >> 3) + 4];                                                \
  }

  f32x4 plo[2], phi[2];
  uint32_t pmb[2];
  PREF(0);
  STAGE(0, 0);
  __syncthreads();

  for (int kt = 0; kt < 64; kt++) {
    int cur = kt & 1;
    if (kt < 63) STAGE(cur ^ 1, kt + 1);
    f32x4 clo[2], chi[2];
    uint32_t cmb[2];
#pragma unroll
    for (int kc = 0; kc < 2; kc++) { clo[kc] = plo[kc]; chi[kc] = phi[kc]; cmb[kc] = pmb[kc]; }
    if (kt < 63) PREF(kt + 1);
#pragma unroll
    for (int kc = 0; kc < 2; kc++) {
      uint32_t b0 = cmb[kc];
      bf16x8 a0;
#pragma unroll
      for (int e = 0; e < 8; e++) {
        float dj = (e < 4) ? clo[kc][e] : chi[kc][e - 4];
        float v0 = fmaxf(Ac + dj, fmaf(0.2f, dj, Bc));
        float p0 = ((b0 >> e) & 1u) ? exp2f(v0) : 0.f;
        zp0 += p0;
        a0[e] = (__bf16)p0;
      }
#pragma unroll
      for (int nt = 0; nt < 8; nt++) {
        int c = nt * 16 + l15;
        int ph = (kc * 4 + l4) ^ (c & 7);
        bf16x8 bfr = *reinterpret_cast<const bf16x8*>(&Bs[cur][c * 64 + ph * 8]);
        acc[nt] = __builtin_amdgcn_mfma_f32_16x16x32_bf16(a0, bfr, acc[nt], 0, 0, 0);
      }
    }
    __syncthreads();
  }
#undef STAGE
#undef PREF

  float z0 = zp0;
  z0 += __shfl_xor(z0, 16);
  z0 += __shfl_xor(z0, 32);

  float zr[4];
#pragma unroll
  for (int r = 0; r < 4; r++) zr[r] = __shfl(z0, l4 * 4 + r);
#pragma unroll
  for (int nt = 0; nt < 8; nt++) {
    int col = cb * 128 + nt * 16 + l15;
#pragma unroll
    for (int r = 0; r < 4; r++) {
      int i = i0 + w * 16 + l4 * 4 + r;
      float val = acc[nt][r] / zr[r];
      float o = val > 0.f ? val : exp2f(val * LOG2E) - 1.f;
      long idx = (long)i * FF + col;
      if (MODE == 0) {
        hout[idx] = f2b(o);
      } else {
        float xn = xin[idx] + o;
        xout[idx] = xn;
        xbout[idx] = f2b(xn);
      }
    }
  }
}

extern "C" void kernel_launch(void* const* d_in, const int* in_sizes, int n_in,
                              void* d_out, int out_size, void* d_ws, size_t ws_size,
                              hipStream_t stream) {
  const float* x = (const float*)d_in[0];
  const int* adj = (const int*)d_in[1];
  const float* W_heads = (const float*)d_in[2];  // [2][4][1024][256]
  const float* a_heads = (const float*)d_in[3];  // [2][4][512]
  const float* W_out = (const float*)d_in[4];    // [2][1024][1024]
  const float* a_out = (const float*)d_in[5];    // [2][2048]
  float* out = (float*)d_out;

  char* ws = (char*)d_ws;
  uint32_t* bits = (uint32_t*)(ws + 0x0);       // 2 MB
  u16* xb = (u16*)(ws + 0x200000);              // 8 MB  bf16 x / x_new
  u16* WcatT = (u16*)(ws + 0xA00000);           // 4 MB  [2][1024 n][1024 k]
  u16* WoutT = (u16*)(ws + 0xE00000);           // 4 MB
  u16* WhT = (u16*)(ws + 0x1200000);            // 8 MB  [1024][4096] (reused for Wh2)
  u16* hbuf = (u16*)(ws + 0x1A00000);           // 8 MB  h bf16 [4096][1024]
  float* xmid = (float*)(ws + 0x2200000);       // 16 MB x after layer 0
  float* s_h = (float*)(ws + 0x3200000);        // [4][4096]
  float* d_h = (float*)(ws + 0x3210000);
  float* m_h = (float*)(ws + 0x3220000);
  float* s_o = (float*)(ws + 0x3230000);        // [4096]
  float* d_o = (float*)(ws + 0x3234000);
  float* m_o = (float*)(ws + 0x3238000);
  float* Z_h = (float*)(ws + 0x3240000);        // [4][4096] f32
  float* Z_o = (float*)(ws + 0x3250000);        // [4096] f32
  u16* Pbuf = (u16*)(ws + 0x3400000);           // 128 MB  [4][4096][4096] bf16
  bool bigws = ws_size >= 0xB400000ull;         // 188.7 MB needed for P path

  k_pack<<<65536, 256, 0, stream>>>(adj, bits);
  k_cvt<<<4096, 256, 0, stream>>>(x, xb, NN * FF / 4);
  k_tconv<<<dim3(32, 8, 8), dim3(32, 8), 0, stream>>>(W_heads, WcatT, 1024, 256);
  k_tconv<<<dim3(32, 32, 2), dim3(32, 8), 0, stream>>>(W_out, WoutT, 1024, 1024);

  for (int l = 0; l < 2; l++) {
    hipMemsetAsync(ws + 0x3200000, 0, 0x3C000, stream);
    k_gemm<<<dim3(32, 8), 256, 0, stream>>>(xb, WcatT + l * 1048576, WhT, FF);
    k_fsd2<<<dim3(16, 8, 4), 256, 0, stream>>>(WhT, a_heads + l * 2048, s_h, d_h, 256);
    k_maxd<4><<<1024, 256, 0, stream>>>(bits, s_h, d_h, m_h);
    if (bigws) {
      k_pgen<<<dim3(1024, 4), 256, 0, stream>>>(bits, s_h, d_h, m_h, Pbuf, Z_h);
      k_pvg<0><<<dim3(64, 8), 256, 0, stream>>>(Pbuf, WhT, Z_h, hbuf, nullptr, nullptr,
                                                nullptr);
    } else {
      k_pv<0><<<dim3(8, 64), 256, 0, stream>>>(bits, WhT, s_h, d_h, m_h, hbuf, nullptr,
                                               nullptr, nullptr);
    }
    k_gemm<<<dim3(32, 8), 256, 0, stream>>>(hbuf, WoutT + l * 1048576, WhT, FF);
    k_fsd2<<<dim3(16, 32, 1), 256, 0, stream>>>(WhT, a_out + l * 2048, s_o, d_o, 1024);
    k_maxd<1><<<1024, 256, 0, stream>>>(bits, s_o, d_o, m_o);
    if (bigws) {
      k_pgen<<<dim3(1024, 1), 256, 0, stream>>>(bits, s_o, d_o, m_o, Pbuf, Z_o);
      k_pvg<1><<<dim3(64, 8), 256, 0, stream>>>(Pbuf, WhT, Z_o, nullptr, l ? xmid : x,
                                                l ? out : xmid, xb);
    } else {
      k_pv<1><<<dim3(8, 64), 256, 0, stream>>>(bits, WhT, s_o, d_o, m_o, nullptr,
                                               l ? xmid : x, l ? out : xmid, xb);
    }
  }
}